// Round 1
// baseline (4596.350 us; speedup 1.0000x reference)
//
#include <hip/hip_runtime.h>

#define USER_N 100000
#define ITEM_N 100000
#define NODE_N (USER_N + ITEM_N)
#define D 64
#define INV_SCALE (1.0f / 16.0f)   // 1/(L+1)^2, L=3

// ---- degree: deg[dst] += 1 over all edges ----
__global__ void deg_kernel(const int* __restrict__ dst, float* __restrict__ deg, int E) {
    int i = blockIdx.x * blockDim.x + threadIdx.x;
    int stride = gridDim.x * blockDim.x;
    for (; i < E; i += stride)
        atomicAdd(&deg[dst[i]], 1.0f);
}

// ---- dis[n] = deg>0 ? rsqrt(deg) : 0  (in place) ----
__global__ void dis_kernel(float* __restrict__ deg) {
    int i = blockIdx.x * blockDim.x + threadIdx.x;
    if (i < NODE_N) {
        float d = deg[i];
        deg[i] = d > 0.0f ? rsqrtf(d) : 0.0f;
    }
}

// ---- X = concat(user,item); out = X * 1/16 (acc init) ----
__global__ void init_kernel(const float* __restrict__ user, const float* __restrict__ item,
                            float* __restrict__ X, float* __restrict__ out) {
    int i = blockIdx.x * blockDim.x + threadIdx.x;
    int stride = gridDim.x * blockDim.x;
    const int total = NODE_N * D;
    for (; i < total; i += stride) {
        float v = (i < USER_N * D) ? user[i] : item[i - USER_N * D];
        X[i] = v;
        out[i] = v * INV_SCALE;
    }
}

// ---- one wave per edge: Xn[dst] += dis[src]*dis[dst] * Xc[src] ----
__global__ void scatter_kernel(const int* __restrict__ src, const int* __restrict__ dst,
                               const float* __restrict__ dis,
                               const float* __restrict__ Xc, float* __restrict__ Xn, int E) {
    int wid  = (blockIdx.x * blockDim.x + threadIdx.x) >> 6;
    int lane = threadIdx.x & 63;
    int nw   = (gridDim.x * blockDim.x) >> 6;
    for (int e = wid; e < E; e += nw) {
        int s = src[e];
        int t = dst[e];
        float nrm = dis[s] * dis[t];
        if (nrm != 0.0f) {
            float v = Xc[(size_t)s * D + lane] * nrm;
            atomicAdd(&Xn[(size_t)t * D + lane], v);
        }
    }
}

// ---- out += Xn * 1/16 ----
__global__ void accum_kernel(const float* __restrict__ Xn, float* __restrict__ out) {
    int i = blockIdx.x * blockDim.x + threadIdx.x;
    int stride = gridDim.x * blockDim.x;
    const int total = NODE_N * D;
    for (; i < total; i += stride)
        out[i] += Xn[i] * INV_SCALE;
}

extern "C" void kernel_launch(void* const* d_in, const int* in_sizes, int n_in,
                              void* d_out, int out_size, void* d_ws, size_t ws_size,
                              hipStream_t stream) {
    const float* user_int = (const float*)d_in[0];
    const float* item_int = (const float*)d_in[1];
    const float* user_geo = (const float*)d_in[2];
    const float* item_geo = (const float*)d_in[3];
    const int*   edge     = (const int*)d_in[4];
    const int E = in_sizes[4] / 2;
    const int* srcv = edge;        // edge_index[0]
    const int* dstv = edge + E;    // edge_index[1]
    float* out = (float*)d_out;

    // workspace layout: deg/dis (N floats) | Xa (N*D) | Xb (N*D)
    char* ws = (char*)d_ws;
    float* deg = (float*)ws;
    size_t xoff = (((size_t)NODE_N * sizeof(float)) + 255) & ~(size_t)255;
    float* Xa = (float*)(ws + xoff);
    float* Xb = Xa + (size_t)NODE_N * D;

    const size_t xbytes = (size_t)NODE_N * D * sizeof(float);

    hipMemsetAsync(deg, 0, (size_t)NODE_N * sizeof(float), stream);
    deg_kernel<<<2048, 256, 0, stream>>>(dstv, deg, E);
    dis_kernel<<<(NODE_N + 255) / 256, 256, 0, stream>>>(deg);

    for (int e = 0; e < 2; ++e) {
        const float* u  = (e == 0) ? user_int : user_geo;
        const float* it = (e == 0) ? item_int : item_geo;
        float* o = out + (size_t)e * NODE_N * D;

        init_kernel<<<4096, 256, 0, stream>>>(u, it, Xa, o);

        float* cur = Xa;
        float* nxt = Xb;
        for (int l = 0; l < 3; ++l) {
            hipMemsetAsync(nxt, 0, xbytes, stream);
            scatter_kernel<<<8192, 256, 0, stream>>>(srcv, dstv, deg, cur, nxt, E);
            accum_kernel<<<4096, 256, 0, stream>>>(nxt, o);
            float* t = cur; cur = nxt; nxt = t;
        }
    }
}

// Round 2
// 1274.262 us; speedup vs baseline: 3.6071x; 3.6071x over previous
//
#include <hip/hip_runtime.h>

#define USER_N 100000
#define ITEM_N 100000
#define NODE_N (USER_N + ITEM_N)
#define D 64
#define INV_SCALE (1.0f / 16.0f)   // 1/(L+1)^2, L=3
#define SCAN_CHUNK 2048            // per-block elements in prefix scan (256 thr * 8)

// ======================= common =======================

// deg_i[dst] += 1 (int)
__global__ void deg_int_kernel(const int* __restrict__ dst, int* __restrict__ deg, int E) {
    int i = blockIdx.x * blockDim.x + threadIdx.x;
    int stride = gridDim.x * blockDim.x;
    for (; i < E; i += stride)
        atomicAdd(&deg[dst[i]], 1);
}

// dis[n] = deg>0 ? rsqrt(deg) : 0
__global__ void dis_kernel(const int* __restrict__ deg, float* __restrict__ dis) {
    int i = blockIdx.x * blockDim.x + threadIdx.x;
    if (i < NODE_N) {
        int d = deg[i];
        dis[i] = d > 0 ? rsqrtf((float)d) : 0.0f;
    }
}

// ======================= CSR build =======================

// phase A: per-block sums of deg
__global__ void scanA_kernel(const int* __restrict__ deg, int* __restrict__ bsum) {
    __shared__ int lds[256];
    int base = blockIdx.x * SCAN_CHUNK + threadIdx.x * 8;
    int s = 0;
    for (int k = 0; k < 8; ++k) {
        int i = base + k;
        s += (i < NODE_N) ? deg[i] : 0;
    }
    lds[threadIdx.x] = s;
    __syncthreads();
    if (threadIdx.x == 0) {
        int t = 0;
        for (int j = 0; j < 256; ++j) t += lds[j];
        bsum[blockIdx.x] = t;
    }
}

// phase B: serial exclusive scan of block sums (NB small), writes row_ptr[N]=E
__global__ void scanB_kernel(int* __restrict__ bsum, int* __restrict__ row_ptr, int NB) {
    if (blockIdx.x == 0 && threadIdx.x == 0) {
        int run = 0;
        for (int b = 0; b < NB; ++b) {
            int t = bsum[b];
            bsum[b] = run;
            run += t;
        }
        row_ptr[NODE_N] = run;
    }
}

// phase C: per-block exclusive scan + block offset -> row_ptr
__global__ void scanC_kernel(const int* __restrict__ deg, const int* __restrict__ bsum,
                             int* __restrict__ row_ptr) {
    __shared__ int lds[256];
    int tid = threadIdx.x;
    int base = blockIdx.x * SCAN_CHUNK + tid * 8;
    int v[8];
    int s = 0;
    for (int k = 0; k < 8; ++k) {
        int i = base + k;
        v[k] = (i < NODE_N) ? deg[i] : 0;
        s += v[k];
    }
    lds[tid] = s;
    __syncthreads();
    int incl = s;
    for (int off = 1; off < 256; off <<= 1) {
        int y = (tid >= off) ? lds[tid - off] : 0;
        __syncthreads();
        incl += y;
        lds[tid] = incl;
        __syncthreads();
    }
    int run = incl - s + bsum[blockIdx.x];  // exclusive prefix for this thread's chunk
    for (int k = 0; k < 8; ++k) {
        int i = base + k;
        if (i < NODE_N) row_ptr[i] = run;
        run += v[k];
    }
}

// fill: col/norm grouped by dst
__global__ void fill_kernel(const int* __restrict__ src, const int* __restrict__ dst,
                            const int* __restrict__ row_ptr, int* __restrict__ cursor,
                            const float* __restrict__ dis,
                            int* __restrict__ col, float* __restrict__ normv, int E) {
    int i = blockIdx.x * blockDim.x + threadIdx.x;
    int stride = gridDim.x * blockDim.x;
    for (; i < E; i += stride) {
        int s = src[i];
        int t = dst[i];
        int p = row_ptr[t] + atomicAdd(&cursor[t], 1);
        col[p] = s;
        normv[p] = dis[s] * dis[t];
    }
}

// ======================= fused path =======================

// X interleaved: X[n*128 + 0..63] = int emb, X[n*128 + 64..127] = geo emb.
// Also initializes out = emb0/16 for both halves.
__global__ void init_fused_kernel(const float* __restrict__ user_int, const float* __restrict__ item_int,
                                  const float* __restrict__ user_geo, const float* __restrict__ item_geo,
                                  float* __restrict__ X, float* __restrict__ out) {
    int i = blockIdx.x * blockDim.x + threadIdx.x;
    int stride = gridDim.x * blockDim.x;
    const int total = NODE_N * 128;
    for (; i < total; i += stride) {
        int n = i >> 7;
        int c = i & 127;
        float v;
        if (c < 64)
            v = (n < USER_N) ? user_int[(size_t)n * 64 + c] : item_int[(size_t)(n - USER_N) * 64 + c];
        else {
            int cc = c - 64;
            v = (n < USER_N) ? user_geo[(size_t)n * 64 + cc] : item_geo[(size_t)(n - USER_N) * 64 + cc];
        }
        X[i] = v;
        size_t obase = (c >= 64) ? (size_t)NODE_N * 64 : 0;
        out[obase + (size_t)n * 64 + (c & 63)] = v * INV_SCALE;
    }
}

// one wave per dst node; gathers both embeddings; fuses acc update.
template <bool LAST>
__global__ void gather_fused_kernel(const int* __restrict__ row_ptr, const int* __restrict__ col,
                                    const float* __restrict__ normv,
                                    const float* __restrict__ Xc, float* __restrict__ Xn,
                                    float* __restrict__ out) {
    int wid = (int)((blockIdx.x * blockDim.x + threadIdx.x) >> 6);
    int lane = threadIdx.x & 63;
    if (wid >= NODE_N) return;
    int beg = row_ptr[wid];
    int end = row_ptr[wid + 1];
    float si = 0.0f, sg = 0.0f;
    for (int chunk = beg; chunk < end; chunk += 64) {
        int e = chunk + lane;
        int c = 0;
        float w = 0.0f;
        if (e < end) { c = col[e]; w = normv[e]; }
        int m = end - chunk;
        if (m > 64) m = 64;
        for (int k = 0; k < m; ++k) {
            int s = __shfl(c, k);
            float ww = __shfl(w, k);
            si += ww * Xc[(size_t)s * 128 + lane];
            sg += ww * Xc[(size_t)s * 128 + 64 + lane];
        }
    }
    if (!LAST) {
        Xn[(size_t)wid * 128 + lane] = si;
        Xn[(size_t)wid * 128 + 64 + lane] = sg;
    }
    out[(size_t)wid * 64 + lane] += si * INV_SCALE;
    out[(size_t)NODE_N * 64 + (size_t)wid * 64 + lane] += sg * INV_SCALE;
}

// ======================= fallback (round-0) path =======================

__global__ void init_kernel(const float* __restrict__ user, const float* __restrict__ item,
                            float* __restrict__ X, float* __restrict__ out) {
    int i = blockIdx.x * blockDim.x + threadIdx.x;
    int stride = gridDim.x * blockDim.x;
    const int total = NODE_N * D;
    for (; i < total; i += stride) {
        float v = (i < USER_N * D) ? user[i] : item[i - USER_N * D];
        X[i] = v;
        out[i] = v * INV_SCALE;
    }
}

__global__ void scatter_kernel(const int* __restrict__ src, const int* __restrict__ dst,
                               const float* __restrict__ dis,
                               const float* __restrict__ Xc, float* __restrict__ Xn, int E) {
    int wid  = (blockIdx.x * blockDim.x + threadIdx.x) >> 6;
    int lane = threadIdx.x & 63;
    int nw   = (gridDim.x * blockDim.x) >> 6;
    for (int e = wid; e < E; e += nw) {
        int s = src[e];
        int t = dst[e];
        float nrm = dis[s] * dis[t];
        if (nrm != 0.0f) {
            float v = Xc[(size_t)s * D + lane] * nrm;
            atomicAdd(&Xn[(size_t)t * D + lane], v);
        }
    }
}

__global__ void accum_kernel(const float* __restrict__ Xn, float* __restrict__ out) {
    int i = blockIdx.x * blockDim.x + threadIdx.x;
    int stride = gridDim.x * blockDim.x;
    const int total = NODE_N * D;
    for (; i < total; i += stride)
        out[i] += Xn[i] * INV_SCALE;
}

// ======================= launch =======================

static inline size_t align256(size_t x) { return (x + 255) & ~(size_t)255; }

extern "C" void kernel_launch(void* const* d_in, const int* in_sizes, int n_in,
                              void* d_out, int out_size, void* d_ws, size_t ws_size,
                              hipStream_t stream) {
    const float* user_int = (const float*)d_in[0];
    const float* item_int = (const float*)d_in[1];
    const float* user_geo = (const float*)d_in[2];
    const float* item_geo = (const float*)d_in[3];
    const int*   edge     = (const int*)d_in[4];
    const int E = in_sizes[4] / 2;
    const int* srcv = edge;
    const int* dstv = edge + E;
    float* out = (float*)d_out;

    const int NB = (NODE_N + SCAN_CHUNK - 1) / SCAN_CHUNK;

    // ws layout
    char* ws = (char*)d_ws;
    size_t off = 0;
    int* deg_i = (int*)(ws + off);      off = align256(off + (size_t)NODE_N * 4);
    float* dis = (float*)(ws + off);    off = align256(off + (size_t)NODE_N * 4);
    int* row_ptr = (int*)(ws + off);    off = align256(off + (size_t)(NODE_N + 1) * 4);
    int* cursor = (int*)(ws + off);     off = align256(off + (size_t)NODE_N * 4);
    int* bsum = (int*)(ws + off);       off = align256(off + (size_t)NB * 4);
    int* col = (int*)(ws + off);        off = align256(off + (size_t)E * 4);
    float* normv = (float*)(ws + off);  off = align256(off + (size_t)E * 4);
    size_t head = off;
    float* Xa = (float*)(ws + off);     off = align256(off + (size_t)NODE_N * 128 * 4);
    float* Xb = (float*)(ws + off);     off = align256(off + (size_t)NODE_N * 128 * 4);
    const size_t FULL_NEED = off;

    // common: deg + dis
    hipMemsetAsync(deg_i, 0, (size_t)NODE_N * 4, stream);
    deg_int_kernel<<<4096, 256, 0, stream>>>(dstv, deg_i, E);
    dis_kernel<<<(NODE_N + 255) / 256, 256, 0, stream>>>(deg_i, dis);

    if (ws_size >= FULL_NEED) {
        // ---- CSR build ----
        scanA_kernel<<<NB, 256, 0, stream>>>(deg_i, bsum);
        scanB_kernel<<<1, 1, 0, stream>>>(bsum, row_ptr, NB);
        scanC_kernel<<<NB, 256, 0, stream>>>(deg_i, bsum, row_ptr);
        hipMemsetAsync(cursor, 0, (size_t)NODE_N * 4, stream);
        fill_kernel<<<8192, 256, 0, stream>>>(srcv, dstv, row_ptr, cursor, dis, col, normv, E);

        // ---- init interleaved X + out ----
        init_fused_kernel<<<8192, 256, 0, stream>>>(user_int, item_int, user_geo, item_geo, Xa, out);

        // ---- 3 fused gather layers ----
        const int gblocks = (NODE_N + 3) / 4;  // 4 waves/block, 1 wave/node
        gather_fused_kernel<false><<<gblocks, 256, 0, stream>>>(row_ptr, col, normv, Xa, Xb, out);
        gather_fused_kernel<false><<<gblocks, 256, 0, stream>>>(row_ptr, col, normv, Xb, Xa, out);
        gather_fused_kernel<true ><<<gblocks, 256, 0, stream>>>(row_ptr, col, normv, Xa, Xb, out);
    } else {
        // ---- fallback: atomic scatter (round-0, known-good) ----
        float* Fa = (float*)(ws + head);
        float* Fb = Fa + (size_t)NODE_N * D;
        const size_t xbytes = (size_t)NODE_N * D * sizeof(float);
        for (int e = 0; e < 2; ++e) {
            const float* u  = (e == 0) ? user_int : user_geo;
            const float* it = (e == 0) ? item_int : item_geo;
            float* o = out + (size_t)e * NODE_N * D;
            init_kernel<<<4096, 256, 0, stream>>>(u, it, Fa, o);
            float* cur = Fa;
            float* nxt = Fb;
            for (int l = 0; l < 3; ++l) {
                hipMemsetAsync(nxt, 0, xbytes, stream);
                scatter_kernel<<<8192, 256, 0, stream>>>(srcv, dstv, dis, cur, nxt, E);
                accum_kernel<<<4096, 256, 0, stream>>>(nxt, o);
                float* t = cur; cur = nxt; nxt = t;
            }
        }
    }
}

// Round 3
// 817.268 us; speedup vs baseline: 5.6240x; 1.5592x over previous
//
#include <hip/hip_runtime.h>
#include <hip/hip_fp16.h>

#define USER_N 100000
#define ITEM_N 100000
#define NODE_N (USER_N + ITEM_N)
#define D 64
#define INV_SCALE (1.0f / 16.0f)   // 1/(L+1)^2, L=3
#define SCAN_CHUNK 2048

// ======================= common =======================

__global__ void deg_int_kernel(const int* __restrict__ dst, int* __restrict__ deg, int E) {
    int i = blockIdx.x * blockDim.x + threadIdx.x;
    int stride = gridDim.x * blockDim.x;
    for (; i < E; i += stride)
        atomicAdd(&deg[dst[i]], 1);
}

__global__ void dis_kernel(const int* __restrict__ deg, float* __restrict__ dis) {
    int i = blockIdx.x * blockDim.x + threadIdx.x;
    if (i < NODE_N) {
        int d = deg[i];
        dis[i] = d > 0 ? rsqrtf((float)d) : 0.0f;
    }
}

// ======================= CSR build =======================

__global__ void scanA_kernel(const int* __restrict__ deg, int* __restrict__ bsum) {
    __shared__ int lds[256];
    int base = blockIdx.x * SCAN_CHUNK + threadIdx.x * 8;
    int s = 0;
    for (int k = 0; k < 8; ++k) {
        int i = base + k;
        s += (i < NODE_N) ? deg[i] : 0;
    }
    lds[threadIdx.x] = s;
    __syncthreads();
    if (threadIdx.x == 0) {
        int t = 0;
        for (int j = 0; j < 256; ++j) t += lds[j];
        bsum[blockIdx.x] = t;
    }
}

__global__ void scanB_kernel(int* __restrict__ bsum, int* __restrict__ row_ptr, int NB) {
    if (blockIdx.x == 0 && threadIdx.x == 0) {
        int run = 0;
        for (int b = 0; b < NB; ++b) {
            int t = bsum[b];
            bsum[b] = run;
            run += t;
        }
        row_ptr[NODE_N] = run;
    }
}

__global__ void scanC_kernel(const int* __restrict__ deg, const int* __restrict__ bsum,
                             int* __restrict__ row_ptr) {
    __shared__ int lds[256];
    int tid = threadIdx.x;
    int base = blockIdx.x * SCAN_CHUNK + tid * 8;
    int v[8];
    int s = 0;
    for (int k = 0; k < 8; ++k) {
        int i = base + k;
        v[k] = (i < NODE_N) ? deg[i] : 0;
        s += v[k];
    }
    lds[tid] = s;
    __syncthreads();
    int incl = s;
    for (int off = 1; off < 256; off <<= 1) {
        int y = (tid >= off) ? lds[tid - off] : 0;
        __syncthreads();
        incl += y;
        lds[tid] = incl;
        __syncthreads();
    }
    int run = incl - s + bsum[blockIdx.x];
    for (int k = 0; k < 8; ++k) {
        int i = base + k;
        if (i < NODE_N) row_ptr[i] = run;
        run += v[k];
    }
}

// fill: packed (col, norm) grouped by dst
__global__ void fill_kernel(const int* __restrict__ src, const int* __restrict__ dst,
                            const int* __restrict__ row_ptr, int* __restrict__ cursor,
                            const float* __restrict__ dis,
                            int2* __restrict__ edges, int E) {
    int i = blockIdx.x * blockDim.x + threadIdx.x;
    int stride = gridDim.x * blockDim.x;
    for (; i < E; i += stride) {
        int s = src[i];
        int t = dst[i];
        int p = row_ptr[t] + atomicAdd(&cursor[t], 1);
        int2 ed;
        ed.x = s;
        ed.y = __float_as_int(dis[s] * dis[t]);
        edges[p] = ed;
    }
}

// ======================= fp16 fused path =======================

// X layout: per node 64 half2 = 128 halfs: [0..31]=int emb (channel pairs), [32..63]=geo.
__global__ void init_h_kernel(const float* __restrict__ user_int, const float* __restrict__ item_int,
                              const float* __restrict__ user_geo, const float* __restrict__ item_geo,
                              __half2* __restrict__ X) {
    int i = blockIdx.x * blockDim.x + threadIdx.x;
    int stride = gridDim.x * blockDim.x;
    const int total = NODE_N * 64;
    for (; i < total; i += stride) {
        int n = i >> 6;
        int c = i & 63;
        float2 f;
        if (c < 32)
            f = (n < USER_N) ? ((const float2*)user_int)[(size_t)n * 32 + c]
                             : ((const float2*)item_int)[(size_t)(n - USER_N) * 32 + c];
        else
            f = (n < USER_N) ? ((const float2*)user_geo)[(size_t)n * 32 + (c - 32)]
                             : ((const float2*)item_geo)[(size_t)(n - USER_N) * 32 + (c - 32)];
        X[i] = __float22half2_rn(f);
    }
}

// one wave per dst node; lane l owns half2 channel-pair l (covers both embeddings).
__global__ void gather_h_kernel(const int* __restrict__ row_ptr, const int2* __restrict__ edges,
                                const __half2* __restrict__ Xc, __half2* __restrict__ Xn) {
    int wid = (int)((blockIdx.x * blockDim.x + threadIdx.x) >> 6);
    int lane = threadIdx.x & 63;
    if (wid >= NODE_N) return;
    int beg = row_ptr[wid];
    int end = row_ptr[wid + 1];
    float ax = 0.0f, ay = 0.0f;
#pragma unroll 4
    for (int e = beg; e < end; ++e) {
        int2 ed = edges[e];                 // wave-uniform address -> broadcast line
        float w = __int_as_float(ed.y);
        float2 f = __half22float2(Xc[(size_t)ed.x * 64 + lane]);
        ax += w * f.x;
        ay += w * f.y;
    }
    Xn[(size_t)wid * 64 + lane] = __float22half2_rn(make_float2(ax, ay));
}

// out = (x0+x1+x2+x3)/16 ; out layout [int all nodes | geo all nodes], fp32
__global__ void epilogue_kernel(const __half2* __restrict__ x0, const __half2* __restrict__ x1,
                                const __half2* __restrict__ x2, const __half2* __restrict__ x3,
                                float2* __restrict__ out) {
    int i = blockIdx.x * blockDim.x + threadIdx.x;
    int stride = gridDim.x * blockDim.x;
    const int total = NODE_N * 64;
    for (; i < total; i += stride) {
        int n = i >> 6;
        int c = i & 63;
        float2 f0 = __half22float2(x0[i]);
        float2 f1 = __half22float2(x1[i]);
        float2 f2 = __half22float2(x2[i]);
        float2 f3 = __half22float2(x3[i]);
        float2 r;
        r.x = (f0.x + f1.x + f2.x + f3.x) * INV_SCALE;
        r.y = (f0.y + f1.y + f2.y + f3.y) * INV_SCALE;
        size_t o = (c < 32) ? ((size_t)n * 32 + c)
                            : ((size_t)NODE_N * 32 + (size_t)n * 32 + (c - 32));
        out[o] = r;
    }
}

// ======================= fallback (round-0) path =======================

__global__ void init_kernel(const float* __restrict__ user, const float* __restrict__ item,
                            float* __restrict__ X, float* __restrict__ out) {
    int i = blockIdx.x * blockDim.x + threadIdx.x;
    int stride = gridDim.x * blockDim.x;
    const int total = NODE_N * D;
    for (; i < total; i += stride) {
        float v = (i < USER_N * D) ? user[i] : item[i - USER_N * D];
        X[i] = v;
        out[i] = v * INV_SCALE;
    }
}

__global__ void scatter_kernel(const int* __restrict__ src, const int* __restrict__ dst,
                               const float* __restrict__ dis,
                               const float* __restrict__ Xc, float* __restrict__ Xn, int E) {
    int wid  = (blockIdx.x * blockDim.x + threadIdx.x) >> 6;
    int lane = threadIdx.x & 63;
    int nw   = (gridDim.x * blockDim.x) >> 6;
    for (int e = wid; e < E; e += nw) {
        int s = src[e];
        int t = dst[e];
        float nrm = dis[s] * dis[t];
        if (nrm != 0.0f) {
            float v = Xc[(size_t)s * D + lane] * nrm;
            atomicAdd(&Xn[(size_t)t * D + lane], v);
        }
    }
}

__global__ void accum_kernel(const float* __restrict__ Xn, float* __restrict__ out) {
    int i = blockIdx.x * blockDim.x + threadIdx.x;
    int stride = gridDim.x * blockDim.x;
    const int total = NODE_N * D;
    for (; i < total; i += stride)
        out[i] += Xn[i] * INV_SCALE;
}

// ======================= launch =======================

static inline size_t align256(size_t x) { return (x + 255) & ~(size_t)255; }

extern "C" void kernel_launch(void* const* d_in, const int* in_sizes, int n_in,
                              void* d_out, int out_size, void* d_ws, size_t ws_size,
                              hipStream_t stream) {
    const float* user_int = (const float*)d_in[0];
    const float* item_int = (const float*)d_in[1];
    const float* user_geo = (const float*)d_in[2];
    const float* item_geo = (const float*)d_in[3];
    const int*   edge     = (const int*)d_in[4];
    const int E = in_sizes[4] / 2;
    const int* srcv = edge;
    const int* dstv = edge + E;
    float* out = (float*)d_out;

    const int NB = (NODE_N + SCAN_CHUNK - 1) / SCAN_CHUNK;

    // ws layout
    char* ws = (char*)d_ws;
    size_t off = 0;
    int* deg_i = (int*)(ws + off);      off = align256(off + (size_t)NODE_N * 4);
    float* dis = (float*)(ws + off);    off = align256(off + (size_t)NODE_N * 4);
    int* row_ptr = (int*)(ws + off);    off = align256(off + (size_t)(NODE_N + 1) * 4);
    int* cursor = (int*)(ws + off);     off = align256(off + (size_t)NODE_N * 4);
    int* bsum = (int*)(ws + off);       off = align256(off + (size_t)NB * 4);
    int2* edges = (int2*)(ws + off);    off = align256(off + (size_t)E * 8);
    size_t head = off;
    __half2* x0 = (__half2*)(ws + off); off = align256(off + (size_t)NODE_N * 64 * 4);
    __half2* x1 = (__half2*)(ws + off); off = align256(off + (size_t)NODE_N * 64 * 4);
    __half2* x2 = (__half2*)(ws + off); off = align256(off + (size_t)NODE_N * 64 * 4);
    __half2* x3 = (__half2*)(ws + off); off = align256(off + (size_t)NODE_N * 64 * 4);
    const size_t FULL_NEED = off;

    hipMemsetAsync(deg_i, 0, (size_t)NODE_N * 4, stream);
    deg_int_kernel<<<4096, 256, 0, stream>>>(dstv, deg_i, E);
    dis_kernel<<<(NODE_N + 255) / 256, 256, 0, stream>>>(deg_i, dis);

    if (ws_size >= FULL_NEED) {
        // CSR build
        scanA_kernel<<<NB, 256, 0, stream>>>(deg_i, bsum);
        scanB_kernel<<<1, 1, 0, stream>>>(bsum, row_ptr, NB);
        scanC_kernel<<<NB, 256, 0, stream>>>(deg_i, bsum, row_ptr);
        hipMemsetAsync(cursor, 0, (size_t)NODE_N * 4, stream);
        fill_kernel<<<8192, 256, 0, stream>>>(srcv, dstv, row_ptr, cursor, dis, edges, E);

        // init x0 (fp16, interleaved)
        init_h_kernel<<<8192, 256, 0, stream>>>(user_int, item_int, user_geo, item_geo, x0);

        // 3 gather layers
        const int gblocks = (NODE_N + 3) / 4;  // 4 waves/block, 1 wave/node
        gather_h_kernel<<<gblocks, 256, 0, stream>>>(row_ptr, edges, x0, x1);
        gather_h_kernel<<<gblocks, 256, 0, stream>>>(row_ptr, edges, x1, x2);
        gather_h_kernel<<<gblocks, 256, 0, stream>>>(row_ptr, edges, x2, x3);

        // epilogue: out = (x0+x1+x2+x3)/16
        epilogue_kernel<<<8192, 256, 0, stream>>>(x0, x1, x2, x3, (float2*)out);
    } else {
        // fallback: atomic scatter (round-0, known-good)
        float* Fa = (float*)(ws + head);
        float* Fb = Fa + (size_t)NODE_N * D;
        const size_t xbytes = (size_t)NODE_N * D * sizeof(float);
        for (int e = 0; e < 2; ++e) {
            const float* u  = (e == 0) ? user_int : user_geo;
            const float* it = (e == 0) ? item_int : item_geo;
            float* o = out + (size_t)e * NODE_N * D;
            init_kernel<<<4096, 256, 0, stream>>>(u, it, Fa, o);
            float* cur = Fa;
            float* nxt = Fb;
            for (int l = 0; l < 3; ++l) {
                hipMemsetAsync(nxt, 0, xbytes, stream);
                scatter_kernel<<<8192, 256, 0, stream>>>(srcv, dstv, dis, cur, nxt, E);
                accum_kernel<<<4096, 256, 0, stream>>>(nxt, o);
                float* t = cur; cur = nxt; nxt = t;
            }
        }
    }
}

// Round 4
// 798.776 us; speedup vs baseline: 5.7542x; 1.0232x over previous
//
#include <hip/hip_runtime.h>
#include <hip/hip_fp16.h>

#define USER_N 100000
#define ITEM_N 100000
#define NODE_N (USER_N + ITEM_N)
#define D 64
#define INV_SCALE (1.0f / 16.0f)   // 1/(L+1)^2, L=3
#define SCAN_CHUNK 2048

// ======================= common =======================

__global__ void deg_int_kernel(const int* __restrict__ dst, int* __restrict__ deg, int E) {
    int i = blockIdx.x * blockDim.x + threadIdx.x;
    int stride = gridDim.x * blockDim.x;
    for (; i < E; i += stride)
        atomicAdd(&deg[dst[i]], 1);
}

__global__ void dis_kernel(const int* __restrict__ deg, float* __restrict__ dis) {
    int i = blockIdx.x * blockDim.x + threadIdx.x;
    if (i < NODE_N) {
        int d = deg[i];
        dis[i] = d > 0 ? rsqrtf((float)d) : 0.0f;
    }
}

// ======================= CSR build =======================

__global__ void scanA_kernel(const int* __restrict__ deg, int* __restrict__ bsum) {
    __shared__ int lds[256];
    int base = blockIdx.x * SCAN_CHUNK + threadIdx.x * 8;
    int s = 0;
    for (int k = 0; k < 8; ++k) {
        int i = base + k;
        s += (i < NODE_N) ? deg[i] : 0;
    }
    lds[threadIdx.x] = s;
    __syncthreads();
    if (threadIdx.x == 0) {
        int t = 0;
        for (int j = 0; j < 256; ++j) t += lds[j];
        bsum[blockIdx.x] = t;
    }
}

__global__ void scanB_kernel(int* __restrict__ bsum, int* __restrict__ row_ptr, int NB) {
    if (blockIdx.x == 0 && threadIdx.x == 0) {
        int run = 0;
        for (int b = 0; b < NB; ++b) {
            int t = bsum[b];
            bsum[b] = run;
            run += t;
        }
        row_ptr[NODE_N] = run;
    }
}

__global__ void scanC_kernel(const int* __restrict__ deg, const int* __restrict__ bsum,
                             int* __restrict__ row_ptr) {
    __shared__ int lds[256];
    int tid = threadIdx.x;
    int base = blockIdx.x * SCAN_CHUNK + tid * 8;
    int v[8];
    int s = 0;
    for (int k = 0; k < 8; ++k) {
        int i = base + k;
        v[k] = (i < NODE_N) ? deg[i] : 0;
        s += v[k];
    }
    lds[tid] = s;
    __syncthreads();
    int incl = s;
    for (int off = 1; off < 256; off <<= 1) {
        int y = (tid >= off) ? lds[tid - off] : 0;
        __syncthreads();
        incl += y;
        lds[tid] = incl;
        __syncthreads();
    }
    int run = incl - s + bsum[blockIdx.x];
    for (int k = 0; k < 8; ++k) {
        int i = base + k;
        if (i < NODE_N) row_ptr[i] = run;
        run += v[k];
    }
}

// fill: col only, grouped by dst
__global__ void fill_kernel(const int* __restrict__ src, const int* __restrict__ dst,
                            const int* __restrict__ row_ptr, int* __restrict__ cursor,
                            int* __restrict__ col, int E) {
    int i = blockIdx.x * blockDim.x + threadIdx.x;
    int stride = gridDim.x * blockDim.x;
    for (; i < E; i += stride) {
        int s = src[i];
        int t = dst[i];
        int p = row_ptr[t] + atomicAdd(&cursor[t], 1);
        col[p] = s;
    }
}

// ======================= fp16 y-substitution path =======================
// y_l = dis * x_l. Gather is a pure unweighted sum:
//   S[t] = sum_{e: dst=t} y[src_e];  y_next[t] = dis[t]^2 * S[t];  x_next[t] = dis[t]*S[t].
// Layout per node: 64 half2 = 128 halfs: [0..31]=int channel-pairs, [32..63]=geo.

__global__ void init_y_kernel(const float* __restrict__ user_int, const float* __restrict__ item_int,
                              const float* __restrict__ user_geo, const float* __restrict__ item_geo,
                              const float* __restrict__ dis, __half2* __restrict__ Y) {
    int i = blockIdx.x * blockDim.x + threadIdx.x;
    int stride = gridDim.x * blockDim.x;
    const int total = NODE_N * 64;
    for (; i < total; i += stride) {
        int n = i >> 6;
        int c = i & 63;
        float2 f;
        if (c < 32)
            f = (n < USER_N) ? ((const float2*)user_int)[(size_t)n * 32 + c]
                             : ((const float2*)item_int)[(size_t)(n - USER_N) * 32 + c];
        else
            f = (n < USER_N) ? ((const float2*)user_geo)[(size_t)n * 32 + (c - 32)]
                             : ((const float2*)item_geo)[(size_t)(n - USER_N) * 32 + (c - 32)];
        float d = dis[n];
        Y[i] = __float22half2_rn(make_float2(f.x * d, f.y * d));
    }
}

// middle layers: Yn[t] = dis[t]^2 * sum y[src]
__global__ void gather_mid_kernel(const int* __restrict__ row_ptr, const int* __restrict__ col,
                                  const float* __restrict__ dis,
                                  const __half2* __restrict__ Yc, __half2* __restrict__ Yn) {
    int wid = (int)((blockIdx.x * blockDim.x + threadIdx.x) >> 6);
    int lane = threadIdx.x & 63;
    if (wid >= NODE_N) return;
    int beg = row_ptr[wid];
    int end = row_ptr[wid + 1];
    float ax = 0.0f, ay = 0.0f;
#pragma unroll 4
    for (int e = beg; e < end; ++e) {
        int s = col[e];
        float2 f = __half22float2(Yc[(size_t)s * 64 + lane]);
        ax += f.x;
        ay += f.y;
    }
    float d = dis[wid];
    float d2 = d * d;
    Yn[(size_t)wid * 64 + lane] = __float22half2_rn(make_float2(ax * d2, ay * d2));
}

// last layer fused with epilogue:
// out[t] = (x0[t] + (y1[t]+y2[t])*sqrt(deg) + dis[t]*S3[t]) / 16
__global__ void gather_last_kernel(const int* __restrict__ row_ptr, const int* __restrict__ col,
                                   const float* __restrict__ dis, const int* __restrict__ deg,
                                   const float* __restrict__ user_int, const float* __restrict__ item_int,
                                   const float* __restrict__ user_geo, const float* __restrict__ item_geo,
                                   const __half2* __restrict__ y1, const __half2* __restrict__ y2,
                                   const __half2* __restrict__ Yc, float2* __restrict__ out) {
    int wid = (int)((blockIdx.x * blockDim.x + threadIdx.x) >> 6);
    int lane = threadIdx.x & 63;
    if (wid >= NODE_N) return;
    int beg = row_ptr[wid];
    int end = row_ptr[wid + 1];
    float ax = 0.0f, ay = 0.0f;
#pragma unroll 4
    for (int e = beg; e < end; ++e) {
        int s = col[e];
        float2 f = __half22float2(Yc[(size_t)s * 64 + lane]);
        ax += f.x;
        ay += f.y;
    }
    float d = dis[wid];
    int dg = deg[wid];
    float sd = dg > 0 ? sqrtf((float)dg) : 0.0f;   // 1/dis
    size_t ridx = (size_t)wid * 64 + lane;
    float2 y1v = __half22float2(y1[ridx]);
    float2 y2v = __half22float2(y2[ridx]);
    int c = lane;
    float2 x0;
    if (c < 32)
        x0 = (wid < USER_N) ? ((const float2*)user_int)[(size_t)wid * 32 + c]
                            : ((const float2*)item_int)[(size_t)(wid - USER_N) * 32 + c];
    else {
        int cc = c - 32;
        x0 = (wid < USER_N) ? ((const float2*)user_geo)[(size_t)wid * 32 + cc]
                            : ((const float2*)item_geo)[(size_t)(wid - USER_N) * 32 + cc];
    }
    float2 r;
    r.x = (x0.x + (y1v.x + y2v.x) * sd + ax * d) * INV_SCALE;
    r.y = (x0.y + (y1v.y + y2v.y) * sd + ay * d) * INV_SCALE;
    size_t o = (c < 32) ? ((size_t)wid * 32 + c)
                        : ((size_t)NODE_N * 32 + (size_t)wid * 32 + (c - 32));
    out[o] = r;
}

// ======================= fallback (round-0) path =======================

__global__ void init_kernel(const float* __restrict__ user, const float* __restrict__ item,
                            float* __restrict__ X, float* __restrict__ out) {
    int i = blockIdx.x * blockDim.x + threadIdx.x;
    int stride = gridDim.x * blockDim.x;
    const int total = NODE_N * D;
    for (; i < total; i += stride) {
        float v = (i < USER_N * D) ? user[i] : item[i - USER_N * D];
        X[i] = v;
        out[i] = v * INV_SCALE;
    }
}

__global__ void scatter_kernel(const int* __restrict__ src, const int* __restrict__ dst,
                               const float* __restrict__ dis,
                               const float* __restrict__ Xc, float* __restrict__ Xn, int E) {
    int wid  = (blockIdx.x * blockDim.x + threadIdx.x) >> 6;
    int lane = threadIdx.x & 63;
    int nw   = (gridDim.x * blockDim.x) >> 6;
    for (int e = wid; e < E; e += nw) {
        int s = src[e];
        int t = dst[e];
        float nrm = dis[s] * dis[t];
        if (nrm != 0.0f) {
            float v = Xc[(size_t)s * D + lane] * nrm;
            atomicAdd(&Xn[(size_t)t * D + lane], v);
        }
    }
}

__global__ void accum_kernel(const float* __restrict__ Xn, float* __restrict__ out) {
    int i = blockIdx.x * blockDim.x + threadIdx.x;
    int stride = gridDim.x * blockDim.x;
    const int total = NODE_N * D;
    for (; i < total; i += stride)
        out[i] += Xn[i] * INV_SCALE;
}

// ======================= launch =======================

static inline size_t align256(size_t x) { return (x + 255) & ~(size_t)255; }

extern "C" void kernel_launch(void* const* d_in, const int* in_sizes, int n_in,
                              void* d_out, int out_size, void* d_ws, size_t ws_size,
                              hipStream_t stream) {
    const float* user_int = (const float*)d_in[0];
    const float* item_int = (const float*)d_in[1];
    const float* user_geo = (const float*)d_in[2];
    const float* item_geo = (const float*)d_in[3];
    const int*   edge     = (const int*)d_in[4];
    const int E = in_sizes[4] / 2;
    const int* srcv = edge;
    const int* dstv = edge + E;
    float* out = (float*)d_out;

    const int NB = (NODE_N + SCAN_CHUNK - 1) / SCAN_CHUNK;

    // ws layout
    char* ws = (char*)d_ws;
    size_t off = 0;
    int* deg_i = (int*)(ws + off);      off = align256(off + (size_t)NODE_N * 4);
    float* dis = (float*)(ws + off);    off = align256(off + (size_t)NODE_N * 4);
    int* row_ptr = (int*)(ws + off);    off = align256(off + (size_t)(NODE_N + 1) * 4);
    int* cursor = (int*)(ws + off);     off = align256(off + (size_t)NODE_N * 4);
    int* bsum = (int*)(ws + off);       off = align256(off + (size_t)NB * 4);
    int* col = (int*)(ws + off);        off = align256(off + (size_t)E * 4);
    size_t head = off;
    __half2* y0 = (__half2*)(ws + off); off = align256(off + (size_t)NODE_N * 64 * 4);
    __half2* y1 = (__half2*)(ws + off); off = align256(off + (size_t)NODE_N * 64 * 4);
    __half2* y2 = (__half2*)(ws + off); off = align256(off + (size_t)NODE_N * 64 * 4);
    const size_t FULL_NEED = off;

    hipMemsetAsync(deg_i, 0, (size_t)NODE_N * 4, stream);
    deg_int_kernel<<<4096, 256, 0, stream>>>(dstv, deg_i, E);
    dis_kernel<<<(NODE_N + 255) / 256, 256, 0, stream>>>(deg_i, dis);

    if (ws_size >= FULL_NEED) {
        // CSR build
        scanA_kernel<<<NB, 256, 0, stream>>>(deg_i, bsum);
        scanB_kernel<<<1, 1, 0, stream>>>(bsum, row_ptr, NB);
        scanC_kernel<<<NB, 256, 0, stream>>>(deg_i, bsum, row_ptr);
        hipMemsetAsync(cursor, 0, (size_t)NODE_N * 4, stream);
        fill_kernel<<<8192, 256, 0, stream>>>(srcv, dstv, row_ptr, cursor, col, E);

        // y0 = dis * x0 (fp16, interleaved int|geo)
        init_y_kernel<<<8192, 256, 0, stream>>>(user_int, item_int, user_geo, item_geo, dis, y0);

        const int gblocks = (NODE_N + 3) / 4;  // 4 waves/block, 1 wave/node
        gather_mid_kernel<<<gblocks, 256, 0, stream>>>(row_ptr, col, dis, y0, y1);
        gather_mid_kernel<<<gblocks, 256, 0, stream>>>(row_ptr, col, dis, y1, y2);
        gather_last_kernel<<<gblocks, 256, 0, stream>>>(row_ptr, col, dis, deg_i,
                                                        user_int, item_int, user_geo, item_geo,
                                                        y1, y2, y2, (float2*)out);
    } else {
        // fallback: atomic scatter (round-0, known-good)
        float* Fa = (float*)(ws + head);
        float* Fb = Fa + (size_t)NODE_N * D;
        const size_t xbytes = (size_t)NODE_N * D * sizeof(float);
        for (int e = 0; e < 2; ++e) {
            const float* u  = (e == 0) ? user_int : user_geo;
            const float* it = (e == 0) ? item_int : item_geo;
            float* o = out + (size_t)e * NODE_N * D;
            init_kernel<<<4096, 256, 0, stream>>>(u, it, Fa, o);
            float* cur = Fa;
            float* nxt = Fb;
            for (int l = 0; l < 3; ++l) {
                hipMemsetAsync(nxt, 0, xbytes, stream);
                scatter_kernel<<<8192, 256, 0, stream>>>(srcv, dstv, dis, cur, nxt, E);
                accum_kernel<<<4096, 256, 0, stream>>>(nxt, o);
                float* t = cur; cur = nxt; nxt = t;
            }
        }
    }
}

// Round 5
// 684.513 us; speedup vs baseline: 6.7148x; 1.1669x over previous
//
#include <hip/hip_runtime.h>
#include <hip/hip_fp16.h>

#define USER_N 100000
#define ITEM_N 100000
#define NODE_N (USER_N + ITEM_N)
#define D 64
#define INV_SCALE (1.0f / 16.0f)   // 1/(L+1)^2, L=3
#define SCAN_CHUNK 2048
#define FILL_BLOCKS 4096
#define INIT_BLOCKS 2048

// ======================= degree + rank =======================

// rank[i] = arrival order of edge i within its dst row; deg[dst] counts.
__global__ void deg_rank_kernel(const int* __restrict__ dst, int* __restrict__ deg,
                                int* __restrict__ rank, int E) {
    int i = blockIdx.x * blockDim.x + threadIdx.x;
    int stride = gridDim.x * blockDim.x;
    for (; i < E; i += stride)
        rank[i] = atomicAdd(&deg[dst[i]], 1);
}

// (fallback path helper)
__global__ void dis_kernel(const int* __restrict__ deg, float* __restrict__ dis) {
    int i = blockIdx.x * blockDim.x + threadIdx.x;
    if (i < NODE_N) {
        int d = deg[i];
        dis[i] = d > 0 ? rsqrtf((float)d) : 0.0f;
    }
}

// ======================= CSR build =======================

__global__ void scanA_kernel(const int* __restrict__ deg, int* __restrict__ bsum) {
    __shared__ int lds[256];
    int base = blockIdx.x * SCAN_CHUNK + threadIdx.x * 8;
    int s = 0;
    for (int k = 0; k < 8; ++k) {
        int i = base + k;
        s += (i < NODE_N) ? deg[i] : 0;
    }
    lds[threadIdx.x] = s;
    __syncthreads();
    if (threadIdx.x == 0) {
        int t = 0;
        for (int j = 0; j < 256; ++j) t += lds[j];
        bsum[blockIdx.x] = t;
    }
}

__global__ void scanB_kernel(int* __restrict__ bsum, int* __restrict__ row_ptr, int NB) {
    if (blockIdx.x == 0 && threadIdx.x == 0) {
        int run = 0;
        for (int b = 0; b < NB; ++b) {
            int t = bsum[b];
            bsum[b] = run;
            run += t;
        }
        row_ptr[NODE_N] = run;
    }
}

// scanC + dis fused: row_ptr[i] = exclusive prefix; dis[i] = rsqrt(deg)
__global__ void scanC_dis_kernel(const int* __restrict__ deg, const int* __restrict__ bsum,
                                 int* __restrict__ row_ptr, float* __restrict__ dis) {
    __shared__ int lds[256];
    int tid = threadIdx.x;
    int base = blockIdx.x * SCAN_CHUNK + tid * 8;
    int v[8];
    int s = 0;
    for (int k = 0; k < 8; ++k) {
        int i = base + k;
        v[k] = (i < NODE_N) ? deg[i] : 0;
        s += v[k];
    }
    lds[tid] = s;
    __syncthreads();
    int incl = s;
    for (int off = 1; off < 256; off <<= 1) {
        int y = (tid >= off) ? lds[tid - off] : 0;
        __syncthreads();
        incl += y;
        lds[tid] = incl;
        __syncthreads();
    }
    int run = incl - s + bsum[blockIdx.x];
    for (int k = 0; k < 8; ++k) {
        int i = base + k;
        if (i < NODE_N) {
            row_ptr[i] = run;
            dis[i] = v[k] > 0 ? rsqrtf((float)v[k]) : 0.0f;
        }
        run += v[k];
    }
}

// ======================= fused fill + init_y =======================
// Y layout per node: 128 halfs: [0..63]=int emb, [64..127]=geo emb. y = dis * x0.
__global__ void fill_init_kernel(const int* __restrict__ src, const int* __restrict__ dst,
                                 const int* __restrict__ rank, const int* __restrict__ row_ptr,
                                 int* __restrict__ col, int E,
                                 const float* __restrict__ user_int, const float* __restrict__ item_int,
                                 const float* __restrict__ user_geo, const float* __restrict__ item_geo,
                                 const float* __restrict__ dis, __half2* __restrict__ Y) {
    if (blockIdx.x < FILL_BLOCKS) {
        int i = blockIdx.x * blockDim.x + threadIdx.x;
        int stride = FILL_BLOCKS * blockDim.x;
        for (; i < E; i += stride) {
            int t = dst[i];
            col[row_ptr[t] + rank[i]] = src[i];
        }
    } else {
        int i = (blockIdx.x - FILL_BLOCKS) * blockDim.x + threadIdx.x;
        int stride = INIT_BLOCKS * blockDim.x;
        const int total = NODE_N * 64;
        for (; i < total; i += stride) {
            int n = i >> 6;
            int c = i & 63;
            float2 f;
            if (c < 32)
                f = (n < USER_N) ? ((const float2*)user_int)[(size_t)n * 32 + c]
                                 : ((const float2*)item_int)[(size_t)(n - USER_N) * 32 + c];
            else
                f = (n < USER_N) ? ((const float2*)user_geo)[(size_t)n * 32 + (c - 32)]
                                 : ((const float2*)item_geo)[(size_t)(n - USER_N) * 32 + (c - 32)];
            float d = dis[n];
            Y[i] = __float22half2_rn(make_float2(f.x * d, f.y * d));
        }
    }
}

// ======================= gathers: 4 edges/wave, 16B/lane =======================

#define RED2(v) { v += __shfl_xor(v, 16); v += __shfl_xor(v, 32); }

// Yn[t] = dis[t]^2 * sum_{src} Yc[src]
__global__ void gather_mid4_kernel(const int* __restrict__ row_ptr, const int* __restrict__ col,
                                   const float* __restrict__ dis,
                                   const __half* __restrict__ Yc, __half* __restrict__ Yn) {
    int wid = (int)((blockIdx.x * blockDim.x + threadIdx.x) >> 6);
    int lane = threadIdx.x & 63;
    int sub = lane >> 4;   // edge slot 0..3
    int ch  = lane & 15;   // 16B chunk 0..15
    if (wid >= NODE_N) return;
    int beg = row_ptr[wid];
    int end = row_ptr[wid + 1];
    float a0x = 0, a0y = 0, a1x = 0, a1y = 0, a2x = 0, a2y = 0, a3x = 0, a3y = 0;
    for (int e0 = beg; e0 < end; e0 += 4) {
        int e = e0 + sub;
        uint4 r = make_uint4(0, 0, 0, 0);
        if (e < end) {
            int s = col[e];
            r = *(const uint4*)(Yc + (((size_t)s) << 7) + (ch << 3));
        }
        const __half2* h = reinterpret_cast<const __half2*>(&r);
        float2 f0 = __half22float2(h[0]);
        float2 f1 = __half22float2(h[1]);
        float2 f2 = __half22float2(h[2]);
        float2 f3 = __half22float2(h[3]);
        a0x += f0.x; a0y += f0.y; a1x += f1.x; a1y += f1.y;
        a2x += f2.x; a2y += f2.y; a3x += f3.x; a3y += f3.y;
    }
    RED2(a0x) RED2(a0y) RED2(a1x) RED2(a1y)
    RED2(a2x) RED2(a2y) RED2(a3x) RED2(a3y)
    if (lane < 16) {
        float d = dis[wid];
        float d2 = d * d;
        __half2 o[4];
        o[0] = __float22half2_rn(make_float2(a0x * d2, a0y * d2));
        o[1] = __float22half2_rn(make_float2(a1x * d2, a1y * d2));
        o[2] = __float22half2_rn(make_float2(a2x * d2, a2y * d2));
        o[3] = __float22half2_rn(make_float2(a3x * d2, a3y * d2));
        *(uint4*)(Yn + (((size_t)wid) << 7) + (ch << 3)) = *(const uint4*)o;
    }
}

// last layer + epilogue:
// out[t] = (x0 + (y1+y2)*sd + S3*dis) / 16, x0 = dg>0 ? y0*sd : inputs
__global__ void gather_last4_kernel(const int* __restrict__ row_ptr, const int* __restrict__ col,
                                    const float* __restrict__ dis, const int* __restrict__ deg,
                                    const float* __restrict__ user_int, const float* __restrict__ item_int,
                                    const float* __restrict__ user_geo, const float* __restrict__ item_geo,
                                    const __half* __restrict__ y0, const __half* __restrict__ y1,
                                    const __half* __restrict__ y2, float* __restrict__ out) {
    int wid = (int)((blockIdx.x * blockDim.x + threadIdx.x) >> 6);
    int lane = threadIdx.x & 63;
    int sub = lane >> 4;
    int ch  = lane & 15;
    if (wid >= NODE_N) return;
    int beg = row_ptr[wid];
    int end = row_ptr[wid + 1];
    float a0x = 0, a0y = 0, a1x = 0, a1y = 0, a2x = 0, a2y = 0, a3x = 0, a3y = 0;
    for (int e0 = beg; e0 < end; e0 += 4) {
        int e = e0 + sub;
        uint4 r = make_uint4(0, 0, 0, 0);
        if (e < end) {
            int s = col[e];
            r = *(const uint4*)(y2 + (((size_t)s) << 7) + (ch << 3));
        }
        const __half2* h = reinterpret_cast<const __half2*>(&r);
        float2 f0 = __half22float2(h[0]);
        float2 f1 = __half22float2(h[1]);
        float2 f2 = __half22float2(h[2]);
        float2 f3 = __half22float2(h[3]);
        a0x += f0.x; a0y += f0.y; a1x += f1.x; a1y += f1.y;
        a2x += f2.x; a2y += f2.y; a3x += f3.x; a3y += f3.y;
    }
    RED2(a0x) RED2(a0y) RED2(a1x) RED2(a1y)
    RED2(a2x) RED2(a2y) RED2(a3x) RED2(a3y)
    if (lane < 16) {
        float S[8] = {a0x, a0y, a1x, a1y, a2x, a2y, a3x, a3y};
        float d = dis[wid];
        int dg = deg[wid];
        float sd = dg > 0 ? sqrtf((float)dg) : 0.0f;
        size_t rbase = (((size_t)wid) << 7) + (ch << 3);
        uint4 r0 = *(const uint4*)(y0 + rbase);
        uint4 r1 = *(const uint4*)(y1 + rbase);
        uint4 r2 = *(const uint4*)(y2 + rbase);
        const __half2* h0 = reinterpret_cast<const __half2*>(&r0);
        const __half2* h1 = reinterpret_cast<const __half2*>(&r1);
        const __half2* h2 = reinterpret_cast<const __half2*>(&r2);
        float res[8];
#pragma unroll
        for (int k = 0; k < 4; ++k) {
            float2 f0 = __half22float2(h0[k]);
            float2 f1 = __half22float2(h1[k]);
            float2 f2 = __half22float2(h2[k]);
            res[2 * k]     = (f0.x * sd + (f1.x + f2.x) * sd + S[2 * k] * d) * INV_SCALE;
            res[2 * k + 1] = (f0.y * sd + (f1.y + f2.y) * sd + S[2 * k + 1] * d) * INV_SCALE;
        }
        if (dg == 0) {
            // x0 must come from the true inputs (y0 is zero here)
            const float* base = (ch < 8)
                ? ((wid < USER_N) ? user_int + (size_t)wid * 64 : item_int + (size_t)(wid - USER_N) * 64)
                : ((wid < USER_N) ? user_geo + (size_t)wid * 64 : item_geo + (size_t)(wid - USER_N) * 64);
            int c0 = (ch & 7) * 8;
#pragma unroll
            for (int j = 0; j < 8; ++j)
                res[j] = (base[c0 + j] + S[j] * d) * INV_SCALE;
        }
        size_t off = (ch < 8) ? ((size_t)wid * 64 + (size_t)ch * 8)
                              : ((size_t)NODE_N * 64 + (size_t)wid * 64 + (size_t)(ch - 8) * 8);
        *(float4*)(out + off)     = make_float4(res[0], res[1], res[2], res[3]);
        *(float4*)(out + off + 4) = make_float4(res[4], res[5], res[6], res[7]);
    }
}

// ======================= fallback (round-0) path =======================

__global__ void init_kernel(const float* __restrict__ user, const float* __restrict__ item,
                            float* __restrict__ X, float* __restrict__ out) {
    int i = blockIdx.x * blockDim.x + threadIdx.x;
    int stride = gridDim.x * blockDim.x;
    const int total = NODE_N * D;
    for (; i < total; i += stride) {
        float v = (i < USER_N * D) ? user[i] : item[i - USER_N * D];
        X[i] = v;
        out[i] = v * INV_SCALE;
    }
}

__global__ void scatter_kernel(const int* __restrict__ src, const int* __restrict__ dst,
                               const float* __restrict__ dis,
                               const float* __restrict__ Xc, float* __restrict__ Xn, int E) {
    int wid  = (blockIdx.x * blockDim.x + threadIdx.x) >> 6;
    int lane = threadIdx.x & 63;
    int nw   = (gridDim.x * blockDim.x) >> 6;
    for (int e = wid; e < E; e += nw) {
        int s = src[e];
        int t = dst[e];
        float nrm = dis[s] * dis[t];
        if (nrm != 0.0f) {
            float v = Xc[(size_t)s * D + lane] * nrm;
            atomicAdd(&Xn[(size_t)t * D + lane], v);
        }
    }
}

__global__ void accum_kernel(const float* __restrict__ Xn, float* __restrict__ out) {
    int i = blockIdx.x * blockDim.x + threadIdx.x;
    int stride = gridDim.x * blockDim.x;
    const int total = NODE_N * D;
    for (; i < total; i += stride)
        out[i] += Xn[i] * INV_SCALE;
}

// ======================= launch =======================

static inline size_t align256(size_t x) { return (x + 255) & ~(size_t)255; }

extern "C" void kernel_launch(void* const* d_in, const int* in_sizes, int n_in,
                              void* d_out, int out_size, void* d_ws, size_t ws_size,
                              hipStream_t stream) {
    const float* user_int = (const float*)d_in[0];
    const float* item_int = (const float*)d_in[1];
    const float* user_geo = (const float*)d_in[2];
    const float* item_geo = (const float*)d_in[3];
    const int*   edge     = (const int*)d_in[4];
    const int E = in_sizes[4] / 2;
    const int* srcv = edge;
    const int* dstv = edge + E;
    float* out = (float*)d_out;

    const int NB = (NODE_N + SCAN_CHUNK - 1) / SCAN_CHUNK;

    // ws layout
    char* ws = (char*)d_ws;
    size_t off = 0;
    int* deg_i = (int*)(ws + off);      off = align256(off + (size_t)NODE_N * 4);
    float* dis = (float*)(ws + off);    off = align256(off + (size_t)NODE_N * 4);
    int* row_ptr = (int*)(ws + off);    off = align256(off + (size_t)(NODE_N + 1) * 4);
    int* bsum = (int*)(ws + off);       off = align256(off + (size_t)NB * 4);
    int* rank = (int*)(ws + off);       off = align256(off + (size_t)E * 4);
    int* col = (int*)(ws + off);        off = align256(off + (size_t)E * 4);
    size_t head = off;
    __half* y0 = (__half*)(ws + off);   off = align256(off + (size_t)NODE_N * 128 * 2);
    __half* y1 = (__half*)(ws + off);   off = align256(off + (size_t)NODE_N * 128 * 2);
    __half* y2 = (__half*)(ws + off);   off = align256(off + (size_t)NODE_N * 128 * 2);
    const size_t FULL_NEED = off;

    hipMemsetAsync(deg_i, 0, (size_t)NODE_N * 4, stream);

    if (ws_size >= FULL_NEED) {
        deg_rank_kernel<<<4096, 256, 0, stream>>>(dstv, deg_i, rank, E);
        scanA_kernel<<<NB, 256, 0, stream>>>(deg_i, bsum);
        scanB_kernel<<<1, 1, 0, stream>>>(bsum, row_ptr, NB);
        scanC_dis_kernel<<<NB, 256, 0, stream>>>(deg_i, bsum, row_ptr, dis);
        fill_init_kernel<<<FILL_BLOCKS + INIT_BLOCKS, 256, 0, stream>>>(
            srcv, dstv, rank, row_ptr, col, E,
            user_int, item_int, user_geo, item_geo, dis, (__half2*)y0);

        const int gblocks = (NODE_N + 3) / 4;  // 4 waves/block, 1 wave/node
        gather_mid4_kernel<<<gblocks, 256, 0, stream>>>(row_ptr, col, dis, y0, y1);
        gather_mid4_kernel<<<gblocks, 256, 0, stream>>>(row_ptr, col, dis, y1, y2);
        gather_last4_kernel<<<gblocks, 256, 0, stream>>>(row_ptr, col, dis, deg_i,
                                                         user_int, item_int, user_geo, item_geo,
                                                         y0, y1, y2, out);
    } else {
        // fallback: atomic scatter (round-0, known-good)
        deg_rank_kernel<<<4096, 256, 0, stream>>>(dstv, deg_i, rank, E);
        dis_kernel<<<(NODE_N + 255) / 256, 256, 0, stream>>>(deg_i, dis);
        float* Fa = (float*)(ws + head);
        float* Fb = Fa + (size_t)NODE_N * D;
        const size_t xbytes = (size_t)NODE_N * D * sizeof(float);
        for (int e = 0; e < 2; ++e) {
            const float* u  = (e == 0) ? user_int : user_geo;
            const float* it = (e == 0) ? item_int : item_geo;
            float* o = out + (size_t)e * NODE_N * D;
            init_kernel<<<4096, 256, 0, stream>>>(u, it, Fa, o);
            float* cur = Fa;
            float* nxt = Fb;
            for (int l = 0; l < 3; ++l) {
                hipMemsetAsync(nxt, 0, xbytes, stream);
                scatter_kernel<<<8192, 256, 0, stream>>>(srcv, dstv, dis, cur, nxt, E);
                accum_kernel<<<4096, 256, 0, stream>>>(nxt, o);
                float* t = cur; cur = nxt; nxt = t;
            }
        }
    }
}